// Round 4
// baseline (425.317 us; speedup 1.0000x reference)
//
#include <hip/hip_runtime.h>
#include <hip/hip_bf16.h>
#include <cstdint>
#include <cstddef>

typedef __bf16 bf16_t;
typedef __attribute__((ext_vector_type(8))) __bf16 bf16x8;
typedef __attribute__((ext_vector_type(4))) __bf16 bf16x4;
typedef __attribute__((ext_vector_type(4))) float f32x4;

#define B_ 2
#define T_ 2048
#define DIM_ 2048
#define H_ 16
#define DH_ 128
#define DD_ 64
#define DQK_ 192              // DH_ + DD_
#define QSTRIDE_ 3072         // H_ * DQK_
#define BT_ 4096              // B_ * T_

__device__ __forceinline__ void gload16(const void* g, void* lds) {
  __builtin_amdgcn_global_load_lds(
      (const __attribute__((address_space(1))) unsigned int*)g,
      (__attribute__((address_space(3))) unsigned int*)lds, 16, 0, 0);
}

// ---------------- cast x (fp32 -> bf16, vectorized) ----------------
struct bf16_4 { bf16_t a, b, c, d; };
__global__ void cast_f32_bf16(const float* __restrict__ in, bf16_t* __restrict__ out, int n4) {
  int i = blockIdx.x * blockDim.x + threadIdx.x;
  if (i >= n4) return;
  float4 v = ((const float4*)in)[i];
  bf16_4 r{(bf16_t)v.x, (bf16_t)v.y, (bf16_t)v.z, (bf16_t)v.w};
  ((bf16_4*)out)[i] = r;
}

// ------------- transpose + cast weight: W (K x N) fp32 -> Wt (Np x K) bf16 -------------
__global__ void transpose_cast(const float* __restrict__ W, bf16_t* __restrict__ Wt,
                               int K, int N, int Np) {
  __shared__ float tile[32][33];
  int k0 = blockIdx.x * 32, n0 = blockIdx.y * 32;
  int tx = threadIdx.x, ty = threadIdx.y;
#pragma unroll
  for (int i = 0; i < 4; ++i) {
    int k = k0 + ty + i * 8, n = n0 + tx;
    float v = (k < K && n < N) ? W[(size_t)k * N + n] : 0.f;
    tile[ty + i * 8][tx] = v;
  }
  __syncthreads();
#pragma unroll
  for (int i = 0; i < 4; ++i) {
    int n = n0 + ty + i * 8, k = k0 + tx;
    if (n < Np && k < K) Wt[(size_t)n * K + k] = (bf16_t)tile[tx][ty + i * 8];
  }
}

// ------------- transpose V: Vbuf[BT][2048] -> Vt[bh=32][128][T] -------------
__global__ void transpose_v(const bf16_t* __restrict__ V, bf16_t* __restrict__ Vt) {
  __shared__ bf16_t tile[64 * 64];
  int id = blockIdx.x;
  int t0 = (id & 31) * 64;
  int d0 = ((id >> 5) & 1) * 64;
  int bh = id >> 6;  // 0..31
  int b = bh >> 4, h = bh & 15;
  int t = threadIdx.x;
#pragma unroll
  for (int it = 0; it < 2; ++it) {
    int idx = it * 256 + t;
    int tt = idx >> 3, c = idx & 7;
    bf16x8 v = *(const bf16x8*)&V[(size_t)(b * T_ + t0 + tt) * 2048 + h * 128 + d0 + c * 8];
    int sw = (tt ^ (tt >> 3)) & 7;
    *(bf16x8*)((char*)tile + tt * 128 + 16 * (c ^ sw)) = v;
  }
  __syncthreads();
#pragma unroll
  for (int it = 0; it < 2; ++it) {
    int idx = it * 256 + t;
    int dr = idx >> 3, c = idx & 7;
    bf16_t tmp[8];
#pragma unroll
    for (int u = 0; u < 8; ++u) {
      int sw = (u ^ c) & 7;
      tmp[u] = *(const bf16_t*)((const char*)tile + (8 * c + u) * 128 + ((2 * dr) ^ (16 * sw)));
    }
    *(bf16x8*)&Vt[((size_t)bh * 128 + d0 + dr) * T_ + t0 + c * 8] = *(bf16x8*)tmp;
  }
}

// ---------------- GEMM: C(MxN) = A(MxK) * Bt(NxK)^T, bf16 in, fp32 acc ----------------
template <int MODE>
__global__ __launch_bounds__(256) void gemm_bt(const bf16_t* __restrict__ A,
                                               const bf16_t* __restrict__ Bt,
                                               void* __restrict__ Cv,
                                               int M, int N, int K, int ldc) {
  __shared__ bf16_t As[128 * 32];
  __shared__ bf16_t Bs[128 * 32];
  const int t = threadIdx.x;
  const int w = t >> 6, l = t & 63, l15 = l & 15, lhi = l >> 4;
  const int m0 = blockIdx.y * 128, n0 = blockIdx.x * 128;
  const int wr = (w >> 1) * 64, wc = (w & 1) * 64;

  f32x4 zero = {0.f, 0.f, 0.f, 0.f};
  f32x4 acc[4][4];
#pragma unroll
  for (int m = 0; m < 4; ++m)
#pragma unroll
    for (int n = 0; n < 4; ++n) acc[m][n] = zero;

  const int e0 = t * 8;
  const int r0 = e0 >> 5, c0 = e0 & 31;
  const int e1 = 2048 + t * 8;
  const int r1 = e1 >> 5, c1 = e1 & 31;

  for (int k0 = 0; k0 < K; k0 += 32) {
    gload16(A + (size_t)(m0 + r0) * K + k0 + c0, &As[e0]);
    gload16(A + (size_t)(m0 + r1) * K + k0 + c1, &As[e1]);
    gload16(Bt + (size_t)(n0 + r0) * K + k0 + c0, &Bs[e0]);
    gload16(Bt + (size_t)(n0 + r1) * K + k0 + c1, &Bs[e1]);
    __syncthreads();
    bf16x8 af[4], bfr[4];
#pragma unroll
    for (int m = 0; m < 4; ++m)
      af[m] = *(const bf16x8*)&As[(wr + m * 16 + l15) * 32 + lhi * 8];
#pragma unroll
    for (int n = 0; n < 4; ++n)
      bfr[n] = *(const bf16x8*)&Bs[(wc + n * 16 + l15) * 32 + lhi * 8];
#pragma unroll
    for (int m = 0; m < 4; ++m)
#pragma unroll
      for (int n = 0; n < 4; ++n)
        acc[m][n] = __builtin_amdgcn_mfma_f32_16x16x32_bf16(af[m], bfr[n], acc[m][n], 0, 0, 0);
    __syncthreads();
  }

#pragma unroll
  for (int m = 0; m < 4; ++m) {
#pragma unroll
    for (int n = 0; n < 4; ++n) {
#pragma unroll
      for (int r = 0; r < 4; ++r) {
        int row = m0 + wr + m * 16 + lhi * 4 + r;
        int col = n0 + wc + n * 16 + l15;
        if (col < N) {
          float v = acc[m][n][r];
          if (MODE == 0) {
            ((bf16_t*)Cv)[(size_t)row * ldc + col] = (bf16_t)v;
          } else if (MODE == 1) {
            ((float*)Cv)[(size_t)row * ldc + col] = v;
          } else {
            ((bf16_t*)Cv)[(size_t)row * QSTRIDE_ + (col >> 7) * DQK_ + (col & 127)] = (bf16_t)v;
          }
        }
      }
    }
  }
}

// ---------------- RoPE epilogues ----------------
__global__ void rope_q(const bf16_t* __restrict__ qr, const float* __restrict__ fr,
                       bf16_t* __restrict__ Q) {
  int idx = blockIdx.x * 256 + threadIdx.x;  // BT_*H_*32
  int j = idx & 31;
  int h = (idx >> 5) & 15;
  int row = idx >> 9;
  int tt = row & (T_ - 1);
  float x1 = (float)qr[(size_t)row * 1024 + h * 64 + 2 * j];
  float x2 = (float)qr[(size_t)row * 1024 + h * 64 + 2 * j + 1];
  float c = fr[tt * 64 + 2 * j], s = fr[tt * 64 + 2 * j + 1];
  bf16_t o0 = (bf16_t)(x1 * c - x2 * s);
  bf16_t o1 = (bf16_t)(x1 * s + x2 * c);
  size_t o = (size_t)row * QSTRIDE_ + h * DQK_ + 128 + 2 * j;
  Q[o] = o0;
  Q[o + 1] = o1;
}

__global__ void rope_k(const bf16_t* __restrict__ kr, const float* __restrict__ fr,
                       bf16_t* __restrict__ Kb) {
  int idx = blockIdx.x * 256 + threadIdx.x;  // BT_*32
  int j = idx & 31;
  int row = idx >> 5;
  int tt = row & (T_ - 1);
  float x1 = (float)kr[(size_t)row * 64 + 2 * j];
  float x2 = (float)kr[(size_t)row * 64 + 2 * j + 1];
  float c = fr[tt * 64 + 2 * j], s = fr[tt * 64 + 2 * j + 1];
  union { bf16_t h2[2]; unsigned u; } pk;
  pk.h2[0] = (bf16_t)(x1 * c - x2 * s);
  pk.h2[1] = (bf16_t)(x1 * s + x2 * c);
#pragma unroll
  for (int h = 0; h < H_; ++h) {
    *(unsigned*)&Kb[(size_t)row * QSTRIDE_ + h * DQK_ + 128 + 2 * j] = pk.u;
  }
}

// ---------------- causal flash attention v3 ----------------
// 512 blocks x 256 threads. Block handles q-tile pair {qp, 31-qp} SEQUENTIALLY
// (33 tile-steps, balanced, single live register set -> no spills).
// K rows 200 bf16 (2-way free), V^T rows 72 (2-way free), P rows 68.
#define KLDB 200
#define VLDB 72
#define PLDB 68

__global__ __launch_bounds__(256, 2) void flash_attn3(const bf16_t* __restrict__ Q,
                                                      const bf16_t* __restrict__ Kb,
                                                      const bf16_t* __restrict__ Vt,
                                                      bf16_t* __restrict__ Ob) {
  __shared__ bf16_t Ks[64 * KLDB];
  __shared__ bf16_t Vs[128 * VLDB];
  __shared__ bf16_t Ps[4][16 * PLDB];

  const int t = threadIdx.x, w = t >> 6, l = t & 63, l15 = l & 15, lhi = l >> 4;
  const int id = blockIdx.x;
  const int xcd = id & 7, sub = id >> 3;
  const int bh = xcd * 4 + (sub >> 4);
  const int qp = sub & 15;
  const int b = bh >> 4, h = bh & 15;
  const int qa = qp, qb = 31 - qp;  // qa < qb always
  const float scale = 0.07216878364870322f;  // 1/sqrt(192)

  // staging thread->slot maps
  int rK[6], cK[6];
#pragma unroll
  for (int i = 0; i < 6; ++i) { int idx = i * 256 + t; rK[i] = idx / 24; cK[i] = idx % 24; }
  const int rVt = t >> 3, cV = t & 7;
  const bf16_t* kbase = Kb + (size_t)b * T_ * QSTRIDE_ + h * DQK_;
  const bf16_t* vbase = Vt + (size_t)bh * DH_ * T_;

  bf16x8 kreg[6], vreg[4];
#define LOAD_TILE(K0)                                                                      \
  do {                                                                                     \
    _Pragma("unroll") for (int i = 0; i < 6; ++i)                                          \
        kreg[i] = *(const bf16x8*)(kbase + (size_t)((K0) + rK[i]) * QSTRIDE_ + cK[i] * 8); \
    _Pragma("unroll") for (int i = 0; i < 4; ++i)                                          \
        vreg[i] = *(const bf16x8*)(vbase + (size_t)(i * 32 + rVt) * T_ + (K0) + cV * 8);   \
  } while (0)
#define WRITE_TILE()                                                                       \
  do {                                                                                     \
    _Pragma("unroll") for (int i = 0; i < 6; ++i)                                          \
        *(bf16x8*)&Ks[rK[i] * KLDB + cK[i] * 8] = kreg[i];                                 \
    _Pragma("unroll") for (int i = 0; i < 4; ++i)                                          \
        *(bf16x8*)&Vs[(i * 32 + rVt) * VLDB + cV * 8] = vreg[i];                           \
  } while (0)

  f32x4 zero = {0.f, 0.f, 0.f, 0.f};

  LOAD_TILE(0);
  WRITE_TILE();
  __syncthreads();

  for (int pass = 0; pass < 2; ++pass) {
    const int qt = pass ? qb : qa;

    // Q fragments for this pass (row = l15 within wave's 16 rows)
    bf16x8 qf[6];
    {
      const bf16_t* qrow = Q + ((size_t)(b * T_ + qt * 64 + w * 16 + l15)) * QSTRIDE_ + h * DQK_;
#pragma unroll
      for (int kc = 0; kc < 6; ++kc) qf[kc] = *(const bf16x8*)(qrow + kc * 32 + lhi * 8);
    }

    float m_r[4], l_r[4];
    f32x4 accO[8];
#pragma unroll
    for (int r = 0; r < 4; ++r) { m_r[r] = -1e30f; l_r[r] = 0.f; }
#pragma unroll
    for (int n = 0; n < 8; ++n) accO[n] = zero;

    for (int kt = 0; kt <= qt; ++kt) {
      const bool last = (kt == qt);
      const bool haveNext = !(pass == 1 && last);
      if (haveNext) LOAD_TILE(last ? 0 : (kt + 1) * 64);  // prefetch (tile 0 for next pass)

      // scores S[16 x 64] per wave
      f32x4 s[4];
#pragma unroll
      for (int n = 0; n < 4; ++n) s[n] = zero;
      __builtin_amdgcn_s_setprio(1);
#pragma unroll
      for (int kc = 0; kc < 6; ++kc) {
#pragma unroll
        for (int n = 0; n < 4; ++n) {
          bf16x8 kf = *(const bf16x8*)&Ks[(n * 16 + l15) * KLDB + kc * 32 + lhi * 8];
          s[n] = __builtin_amdgcn_mfma_f32_16x16x32_bf16(qf[kc], kf, s[n], 0, 0, 0);
        }
      }
      __builtin_amdgcn_s_setprio(0);

      // mask + softmax
#pragma unroll
      for (int n = 0; n < 4; ++n)
#pragma unroll
        for (int r = 0; r < 4; ++r) {
          float v = s[n][r] * scale;
          if (last) {
            int qq = w * 16 + lhi * 4 + r;
            int kk = n * 16 + l15;
            if (kk > qq) v = -1e30f;
          }
          s[n][r] = v;
        }
      float mn[4], corr[4];
#pragma unroll
      for (int r = 0; r < 4; ++r) {
        float v = fmaxf(fmaxf(s[0][r], s[1][r]), fmaxf(s[2][r], s[3][r]));
#pragma unroll
        for (int off = 1; off < 16; off <<= 1) v = fmaxf(v, __shfl_xor(v, off, 64));
        mn[r] = fmaxf(m_r[r], v);
        corr[r] = __expf(m_r[r] - mn[r]);
        m_r[r] = mn[r];
      }
      float rs[4] = {0.f, 0.f, 0.f, 0.f};
#pragma unroll
      for (int n = 0; n < 4; ++n)
#pragma unroll
        for (int r = 0; r < 4; ++r) {
          float p = __expf(s[n][r] - mn[r]);
          rs[r] += p;
          Ps[w][(lhi * 4 + r) * PLDB + n * 16 + l15] = (bf16_t)p;
        }
#pragma unroll
      for (int r = 0; r < 4; ++r) {
        float v = rs[r];
#pragma unroll
        for (int off = 1; off < 16; off <<= 1) v += __shfl_xor(v, off, 64);
        l_r[r] = l_r[r] * corr[r] + v;
      }
#pragma unroll
      for (int n = 0; n < 8; ++n)
#pragma unroll
        for (int r = 0; r < 4; ++r) accO[n][r] *= corr[r];

      // PV: O += P(16x64) @ V(64x128)
      __builtin_amdgcn_s_setprio(1);
#pragma unroll
      for (int kc = 0; kc < 2; ++kc) {
        bf16x4 p0 = *(const bf16x4*)&Ps[w][l15 * PLDB + kc * 32 + lhi * 8];
        bf16x4 p1 = *(const bf16x4*)&Ps[w][l15 * PLDB + kc * 32 + lhi * 8 + 4];
        bf16x8 pf = __builtin_shufflevector(p0, p1, 0, 1, 2, 3, 4, 5, 6, 7);
#pragma unroll
        for (int n = 0; n < 8; ++n) {
          bf16x8 vf = *(const bf16x8*)&Vs[(n * 16 + l15) * VLDB + kc * 32 + lhi * 8];
          accO[n] = __builtin_amdgcn_mfma_f32_16x16x32_bf16(pf, vf, accO[n], 0, 0, 0);
        }
      }
      __builtin_amdgcn_s_setprio(0);

      __syncthreads();            // all LDS reads of tile kt done
      if (haveNext) WRITE_TILE(); // publish next tile
      __syncthreads();
    }

    // store O for this pass
    {
      float inv[4];
#pragma unroll
      for (int r = 0; r < 4; ++r) inv[r] = 1.0f / l_r[r];
#pragma unroll
      for (int n = 0; n < 8; ++n)
#pragma unroll
        for (int r = 0; r < 4; ++r) {
          size_t row = (size_t)(b * T_ + qt * 64 + w * 16 + lhi * 4 + r);
          Ob[row * (H_ * DH_) + h * DH_ + n * 16 + l15] = (bf16_t)(accO[n][r] * inv[r]);
        }
    }
  }
#undef LOAD_TILE
#undef WRITE_TILE
}

// ---------------- host ----------------
extern "C" void kernel_launch(void* const* d_in, const int* in_sizes, int n_in,
                              void* d_out, int out_size, void* d_ws, size_t ws_size,
                              hipStream_t stream) {
  (void)in_sizes; (void)n_in; (void)out_size; (void)ws_size;
  const float* x    = (const float*)d_in[0];
  const float* fr   = (const float*)d_in[1];
  // d_in[2] = mask (unused; causal handled analytically)
  const float* Wdq  = (const float*)d_in[3];
  const float* Wuq  = (const float*)d_in[4];
  const float* Wdkv = (const float*)d_in[5];
  const float* Wuk  = (const float*)d_in[6];
  const float* Wuv  = (const float*)d_in[7];
  const float* Wqr  = (const float*)d_in[8];
  const float* Wkr  = (const float*)d_in[9];
  const float* Wo   = (const float*)d_in[10];
  float* out = (float*)d_out;

  char* ws = (char*)d_ws;
  size_t off = 0;
  auto alloc = [&](size_t bytes) -> void* {
    void* p = ws + off;
    off += (bytes + 255) & ~(size_t)255;
    return p;
  };
  bf16_t* x_bf   = (bf16_t*)alloc((size_t)BT_ * DIM_ * 2);
  bf16_t* Wdq_t  = (bf16_t*)alloc((size_t)512 * 2048 * 2);
  bf16_t* Wdkv_t = (bf16_t*)alloc((size_t)512 * 2048 * 2);
  bf16_t* Wqr_t  = (bf16_t*)alloc((size_t)1024 * 512 * 2);
  bf16_t* Wkr_t  = (bf16_t*)alloc((size_t)128 * 2048 * 2);   // padded 64 -> 128 rows
  bf16_t* Wuq_t  = (bf16_t*)alloc((size_t)2048 * 512 * 2);
  bf16_t* Wuk_t  = (bf16_t*)alloc((size_t)2048 * 512 * 2);
  bf16_t* Wuv_t  = (bf16_t*)alloc((size_t)2048 * 512 * 2);
  bf16_t* Wo_t   = (bf16_t*)alloc((size_t)2048 * 2048 * 2);
  bf16_t* q_c    = (bf16_t*)alloc((size_t)BT_ * 512 * 2);
  bf16_t* kv_c   = (bf16_t*)alloc((size_t)BT_ * 512 * 2);
  bf16_t* q_rb   = (bf16_t*)alloc((size_t)BT_ * 1024 * 2);
  bf16_t* k_rb   = (bf16_t*)alloc((size_t)BT_ * 64 * 2);
  bf16_t* Qbuf   = (bf16_t*)alloc((size_t)BT_ * QSTRIDE_ * 2);
  bf16_t* Kbuf   = (bf16_t*)alloc((size_t)BT_ * QSTRIDE_ * 2);
  bf16_t* Vbuf   = (bf16_t*)alloc((size_t)BT_ * 2048 * 2);
  bf16_t* Vt_g   = (bf16_t*)alloc((size_t)BT_ * 2048 * 2);
  bf16_t* AObuf  = (bf16_t*)alloc((size_t)BT_ * 2048 * 2);

  dim3 tb(32, 8);
  cast_f32_bf16<<<(BT_ * DIM_ / 4 + 255) / 256, 256, 0, stream>>>(x, x_bf, BT_ * DIM_ / 4);
  transpose_cast<<<dim3(64, 16), tb, 0, stream>>>(Wdq,  Wdq_t,  2048, 512, 512);
  transpose_cast<<<dim3(64, 16), tb, 0, stream>>>(Wdkv, Wdkv_t, 2048, 512, 512);
  transpose_cast<<<dim3(16, 32), tb, 0, stream>>>(Wqr,  Wqr_t,  512, 1024, 1024);
  transpose_cast<<<dim3(64, 4),  tb, 0, stream>>>(Wkr,  Wkr_t,  2048, 64, 128);
  transpose_cast<<<dim3(16, 64), tb, 0, stream>>>(Wuq,  Wuq_t,  512, 2048, 2048);
  transpose_cast<<<dim3(16, 64), tb, 0, stream>>>(Wuk,  Wuk_t,  512, 2048, 2048);
  transpose_cast<<<dim3(16, 64), tb, 0, stream>>>(Wuv,  Wuv_t,  512, 2048, 2048);
  transpose_cast<<<dim3(64, 64), tb, 0, stream>>>(Wo,   Wo_t,   2048, 2048, 2048);

  // projections
  gemm_bt<0><<<dim3(4, 32),  256, 0, stream>>>(x_bf, Wdq_t,  q_c,  BT_, 512, 2048, 512);
  gemm_bt<0><<<dim3(4, 32),  256, 0, stream>>>(x_bf, Wdkv_t, kv_c, BT_, 512, 2048, 512);
  gemm_bt<0><<<dim3(8, 32),  256, 0, stream>>>(q_c,  Wqr_t,  q_rb, BT_, 1024, 512, 1024);
  gemm_bt<0><<<dim3(1, 32),  256, 0, stream>>>(x_bf, Wkr_t,  k_rb, BT_, 64, 2048, 64);
  gemm_bt<2><<<dim3(16, 32), 256, 0, stream>>>(q_c,  Wuq_t,  Qbuf, BT_, 2048, 512, 0);
  gemm_bt<2><<<dim3(16, 32), 256, 0, stream>>>(kv_c, Wuk_t,  Kbuf, BT_, 2048, 512, 0);
  gemm_bt<0><<<dim3(16, 32), 256, 0, stream>>>(kv_c, Wuv_t,  Vbuf, BT_, 2048, 512, 2048);

  transpose_v<<<2048, 256, 0, stream>>>(Vbuf, Vt_g);

  rope_q<<<(BT_ * H_ * 32) / 256, 256, 0, stream>>>(q_rb, fr, Qbuf);
  rope_k<<<(BT_ * 32) / 256, 256, 0, stream>>>(k_rb, fr, Kbuf);

  flash_attn3<<<512, 256, 0, stream>>>(Qbuf, Kbuf, Vt_g, AObuf);

  // output projection -> fp32
  gemm_bt<1><<<dim3(16, 32), 256, 0, stream>>>(AObuf, Wo_t, out, BT_, 2048, 2048, 2048);
}

// Round 5
// 324.314 us; speedup vs baseline: 1.3114x; 1.3114x over previous
//
#include <hip/hip_runtime.h>
#include <hip/hip_bf16.h>
#include <cstdint>
#include <cstddef>

typedef __bf16 bf16_t;
typedef __attribute__((ext_vector_type(8))) __bf16 bf16x8;
typedef __attribute__((ext_vector_type(4))) __bf16 bf16x4;
typedef __attribute__((ext_vector_type(4))) float f32x4;

#define B_ 2
#define T_ 2048
#define DIM_ 2048
#define H_ 16
#define DH_ 128
#define DD_ 64
#define DQK_ 192              // DH_ + DD_
#define QSTRIDE_ 3072         // H_ * DQK_
#define BT_ 4096              // B_ * T_

__device__ __forceinline__ void gload16(const void* g, void* lds) {
  __builtin_amdgcn_global_load_lds(
      (const __attribute__((address_space(1))) unsigned int*)g,
      (__attribute__((address_space(3))) unsigned int*)lds, 16, 0, 0);
}

// ---------------- cast x (fp32 -> bf16, vectorized) ----------------
struct bf16_4 { bf16_t a, b, c, d; };
__global__ void cast_f32_bf16(const float* __restrict__ in, bf16_t* __restrict__ out, int n4) {
  int i = blockIdx.x * blockDim.x + threadIdx.x;
  if (i >= n4) return;
  float4 v = ((const float4*)in)[i];
  bf16_4 r{(bf16_t)v.x, (bf16_t)v.y, (bf16_t)v.z, (bf16_t)v.w};
  ((bf16_4*)out)[i] = r;
}

// ------------- transpose + cast weight: W (K x N) fp32 -> Wt (Np x K) bf16 -------------
__global__ void transpose_cast(const float* __restrict__ W, bf16_t* __restrict__ Wt,
                               int K, int N, int Np) {
  __shared__ float tile[32][33];
  int k0 = blockIdx.x * 32, n0 = blockIdx.y * 32;
  int tx = threadIdx.x, ty = threadIdx.y;
#pragma unroll
  for (int i = 0; i < 4; ++i) {
    int k = k0 + ty + i * 8, n = n0 + tx;
    float v = (k < K && n < N) ? W[(size_t)k * N + n] : 0.f;
    tile[ty + i * 8][tx] = v;
  }
  __syncthreads();
#pragma unroll
  for (int i = 0; i < 4; ++i) {
    int n = n0 + ty + i * 8, k = k0 + tx;
    if (n < Np && k < K) Wt[(size_t)n * K + k] = (bf16_t)tile[tx][ty + i * 8];
  }
}

// ------------- transpose V: Vbuf[BT][2048] -> Vt[bh=32][128][T] -------------
__global__ void transpose_v(const bf16_t* __restrict__ V, bf16_t* __restrict__ Vt) {
  __shared__ bf16_t tile[64 * 64];
  int id = blockIdx.x;
  int t0 = (id & 31) * 64;
  int d0 = ((id >> 5) & 1) * 64;
  int bh = id >> 6;  // 0..31
  int b = bh >> 4, h = bh & 15;
  int t = threadIdx.x;
#pragma unroll
  for (int it = 0; it < 2; ++it) {
    int idx = it * 256 + t;
    int tt = idx >> 3, c = idx & 7;
    bf16x8 v = *(const bf16x8*)&V[(size_t)(b * T_ + t0 + tt) * 2048 + h * 128 + d0 + c * 8];
    int sw = (tt ^ (tt >> 3)) & 7;
    *(bf16x8*)((char*)tile + tt * 128 + 16 * (c ^ sw)) = v;
  }
  __syncthreads();
#pragma unroll
  for (int it = 0; it < 2; ++it) {
    int idx = it * 256 + t;
    int dr = idx >> 3, c = idx & 7;
    bf16_t tmp[8];
#pragma unroll
    for (int u = 0; u < 8; ++u) {
      int sw = (u ^ c) & 7;
      tmp[u] = *(const bf16_t*)((const char*)tile + (8 * c + u) * 128 + ((2 * dr) ^ (16 * sw)));
    }
    *(bf16x8*)&Vt[((size_t)bh * 128 + d0 + dr) * T_ + t0 + c * 8] = *(bf16x8*)tmp;
  }
}

// ---------------- GEMM: C = A(MxK) * Bt(NxK)^T, bf16 in, fp32 acc ----------------
// MODE 1: store fp32 to C0, row stride ldc
// MODE 3: col<512 -> C0 (q_c, ld 512); col<1024 -> C1 (kv_c, ld 512); col<1088 -> C2 (k_rb, ld 64); else skip
// MODE 4: col<2048 -> C0 head-interleaved (Qbuf); else -> C1 plain ld 1024 (q_rb)
// MODE 5: col<2048 -> C0 head-interleaved (Kbuf); else -> C1 plain ld 2048 (Vbuf)
template <int MODE>
__global__ __launch_bounds__(256) void gemm_bt(const bf16_t* __restrict__ A,
                                               const bf16_t* __restrict__ Bt,
                                               void* __restrict__ C0v,
                                               void* __restrict__ C1v,
                                               void* __restrict__ C2v,
                                               int M, int N, int K, int ldc) {
  __shared__ bf16_t As[128 * 32];
  __shared__ bf16_t Bs[128 * 32];
  const int t = threadIdx.x;
  const int w = t >> 6, l = t & 63, l15 = l & 15, lhi = l >> 4;
  const int m0 = blockIdx.y * 128, n0 = blockIdx.x * 128;
  const int wr = (w >> 1) * 64, wc = (w & 1) * 64;

  f32x4 zero = {0.f, 0.f, 0.f, 0.f};
  f32x4 acc[4][4];
#pragma unroll
  for (int m = 0; m < 4; ++m)
#pragma unroll
    for (int n = 0; n < 4; ++n) acc[m][n] = zero;

  const int e0 = t * 8;
  const int r0 = e0 >> 5, c0 = e0 & 31;
  const int e1 = 2048 + t * 8;
  const int r1 = e1 >> 5, c1 = e1 & 31;

  for (int k0 = 0; k0 < K; k0 += 32) {
    gload16(A + (size_t)(m0 + r0) * K + k0 + c0, &As[e0]);
    gload16(A + (size_t)(m0 + r1) * K + k0 + c1, &As[e1]);
    gload16(Bt + (size_t)(n0 + r0) * K + k0 + c0, &Bs[e0]);
    gload16(Bt + (size_t)(n0 + r1) * K + k0 + c1, &Bs[e1]);
    __syncthreads();
    bf16x8 af[4], bfr[4];
#pragma unroll
    for (int m = 0; m < 4; ++m)
      af[m] = *(const bf16x8*)&As[(wr + m * 16 + l15) * 32 + lhi * 8];
#pragma unroll
    for (int n = 0; n < 4; ++n)
      bfr[n] = *(const bf16x8*)&Bs[(wc + n * 16 + l15) * 32 + lhi * 8];
#pragma unroll
    for (int m = 0; m < 4; ++m)
#pragma unroll
      for (int n = 0; n < 4; ++n)
        acc[m][n] = __builtin_amdgcn_mfma_f32_16x16x32_bf16(af[m], bfr[n], acc[m][n], 0, 0, 0);
    __syncthreads();
  }

#pragma unroll
  for (int m = 0; m < 4; ++m) {
#pragma unroll
    for (int n = 0; n < 4; ++n) {
#pragma unroll
      for (int r = 0; r < 4; ++r) {
        int row = m0 + wr + m * 16 + lhi * 4 + r;
        int col = n0 + wc + n * 16 + l15;
        float v = acc[m][n][r];
        if (MODE == 1) {
          ((float*)C0v)[(size_t)row * ldc + col] = v;
        } else if (MODE == 3) {
          if (col < 512)       ((bf16_t*)C0v)[(size_t)row * 512 + col] = (bf16_t)v;
          else if (col < 1024) ((bf16_t*)C1v)[(size_t)row * 512 + (col - 512)] = (bf16_t)v;
          else if (col < 1088) ((bf16_t*)C2v)[(size_t)row * 64 + (col - 1024)] = (bf16_t)v;
        } else if (MODE == 4) {
          if (col < 2048) ((bf16_t*)C0v)[(size_t)row * QSTRIDE_ + (col >> 7) * DQK_ + (col & 127)] = (bf16_t)v;
          else            ((bf16_t*)C1v)[(size_t)row * 1024 + (col - 2048)] = (bf16_t)v;
        } else if (MODE == 5) {
          if (col < 2048) ((bf16_t*)C0v)[(size_t)row * QSTRIDE_ + (col >> 7) * DQK_ + (col & 127)] = (bf16_t)v;
          else            ((bf16_t*)C1v)[(size_t)row * 2048 + (col - 2048)] = (bf16_t)v;
        }
      }
    }
  }
}

// ---------------- RoPE epilogues ----------------
__global__ void rope_q(const bf16_t* __restrict__ qr, const float* __restrict__ fr,
                       bf16_t* __restrict__ Q) {
  int idx = blockIdx.x * 256 + threadIdx.x;  // BT_*H_*32
  int j = idx & 31;
  int h = (idx >> 5) & 15;
  int row = idx >> 9;
  int tt = row & (T_ - 1);
  float x1 = (float)qr[(size_t)row * 1024 + h * 64 + 2 * j];
  float x2 = (float)qr[(size_t)row * 1024 + h * 64 + 2 * j + 1];
  float c = fr[tt * 64 + 2 * j], s = fr[tt * 64 + 2 * j + 1];
  bf16_t o0 = (bf16_t)(x1 * c - x2 * s);
  bf16_t o1 = (bf16_t)(x1 * s + x2 * c);
  size_t o = (size_t)row * QSTRIDE_ + h * DQK_ + 128 + 2 * j;
  Q[o] = o0;
  Q[o + 1] = o1;
}

__global__ void rope_k(const bf16_t* __restrict__ kr, const float* __restrict__ fr,
                       bf16_t* __restrict__ Kb) {
  int idx = blockIdx.x * 256 + threadIdx.x;  // BT_*32
  int j = idx & 31;
  int row = idx >> 5;
  int tt = row & (T_ - 1);
  float x1 = (float)kr[(size_t)row * 64 + 2 * j];
  float x2 = (float)kr[(size_t)row * 64 + 2 * j + 1];
  float c = fr[tt * 64 + 2 * j], s = fr[tt * 64 + 2 * j + 1];
  union { bf16_t h2[2]; unsigned u; } pk;
  pk.h2[0] = (bf16_t)(x1 * c - x2 * s);
  pk.h2[1] = (bf16_t)(x1 * s + x2 * c);
#pragma unroll
  for (int h = 0; h < H_; ++h) {
    *(unsigned*)&Kb[(size_t)row * QSTRIDE_ + h * DQK_ + 128 + 2 * j] = pk.u;
  }
}

// ---------------- causal flash attention v3 ----------------
// 512 blocks x 256 threads. Block handles q-tile pair {qp, 31-qp} SEQUENTIALLY
// (33 tile-steps, balanced, single live register set -> no spills).
#define KLDB 200
#define VLDB 72
#define PLDB 68

__global__ __launch_bounds__(256, 2) void flash_attn3(const bf16_t* __restrict__ Q,
                                                      const bf16_t* __restrict__ Kb,
                                                      const bf16_t* __restrict__ Vt,
                                                      bf16_t* __restrict__ Ob) {
  __shared__ bf16_t Ks[64 * KLDB];
  __shared__ bf16_t Vs[128 * VLDB];
  __shared__ bf16_t Ps[4][16 * PLDB];

  const int t = threadIdx.x, w = t >> 6, l = t & 63, l15 = l & 15, lhi = l >> 4;
  const int id = blockIdx.x;
  const int xcd = id & 7, sub = id >> 3;
  const int bh = xcd * 4 + (sub >> 4);
  const int qp = sub & 15;
  const int b = bh >> 4, h = bh & 15;
  const int qa = qp, qb = 31 - qp;  // qa < qb always
  const float scale = 0.07216878364870322f;  // 1/sqrt(192)

  // staging thread->slot maps
  int rK[6], cK[6];
#pragma unroll
  for (int i = 0; i < 6; ++i) { int idx = i * 256 + t; rK[i] = idx / 24; cK[i] = idx % 24; }
  const int rVt = t >> 3, cV = t & 7;
  const bf16_t* kbase = Kb + (size_t)b * T_ * QSTRIDE_ + h * DQK_;
  const bf16_t* vbase = Vt + (size_t)bh * DH_ * T_;

  bf16x8 kreg[6], vreg[4];
#define LOAD_TILE(K0)                                                                      \
  do {                                                                                     \
    _Pragma("unroll") for (int i = 0; i < 6; ++i)                                          \
        kreg[i] = *(const bf16x8*)(kbase + (size_t)((K0) + rK[i]) * QSTRIDE_ + cK[i] * 8); \
    _Pragma("unroll") for (int i = 0; i < 4; ++i)                                          \
        vreg[i] = *(const bf16x8*)(vbase + (size_t)(i * 32 + rVt) * T_ + (K0) + cV * 8);   \
  } while (0)
#define WRITE_TILE()                                                                       \
  do {                                                                                     \
    _Pragma("unroll") for (int i = 0; i < 6; ++i)                                          \
        *(bf16x8*)&Ks[rK[i] * KLDB + cK[i] * 8] = kreg[i];                                 \
    _Pragma("unroll") for (int i = 0; i < 4; ++i)                                          \
        *(bf16x8*)&Vs[(i * 32 + rVt) * VLDB + cV * 8] = vreg[i];                           \
  } while (0)

  f32x4 zero = {0.f, 0.f, 0.f, 0.f};

  LOAD_TILE(0);
  WRITE_TILE();
  __syncthreads();

  for (int pass = 0; pass < 2; ++pass) {
    const int qt = pass ? qb : qa;

    bf16x8 qf[6];
    {
      const bf16_t* qrow = Q + ((size_t)(b * T_ + qt * 64 + w * 16 + l15)) * QSTRIDE_ + h * DQK_;
#pragma unroll
      for (int kc = 0; kc < 6; ++kc) qf[kc] = *(const bf16x8*)(qrow + kc * 32 + lhi * 8);
    }

    float m_r[4], l_r[4];
    f32x4 accO[8];
#pragma unroll
    for (int r = 0; r < 4; ++r) { m_r[r] = -1e30f; l_r[r] = 0.f; }
#pragma unroll
    for (int n = 0; n < 8; ++n) accO[n] = zero;

    for (int kt = 0; kt <= qt; ++kt) {
      const bool last = (kt == qt);
      const bool haveNext = !(pass == 1 && last);
      if (haveNext) LOAD_TILE(last ? 0 : (kt + 1) * 64);  // prefetch (tile 0 for next pass)

      f32x4 s[4];
#pragma unroll
      for (int n = 0; n < 4; ++n) s[n] = zero;
      __builtin_amdgcn_s_setprio(1);
#pragma unroll
      for (int kc = 0; kc < 6; ++kc) {
#pragma unroll
        for (int n = 0; n < 4; ++n) {
          bf16x8 kf = *(const bf16x8*)&Ks[(n * 16 + l15) * KLDB + kc * 32 + lhi * 8];
          s[n] = __builtin_amdgcn_mfma_f32_16x16x32_bf16(qf[kc], kf, s[n], 0, 0, 0);
        }
      }
      __builtin_amdgcn_s_setprio(0);

#pragma unroll
      for (int n = 0; n < 4; ++n)
#pragma unroll
        for (int r = 0; r < 4; ++r) {
          float v = s[n][r] * scale;
          if (last) {
            int qq = w * 16 + lhi * 4 + r;
            int kk = n * 16 + l15;
            if (kk > qq) v = -1e30f;
          }
          s[n][r] = v;
        }
      float mn[4], corr[4];
#pragma unroll
      for (int r = 0; r < 4; ++r) {
        float v = fmaxf(fmaxf(s[0][r], s[1][r]), fmaxf(s[2][r], s[3][r]));
#pragma unroll
        for (int off = 1; off < 16; off <<= 1) v = fmaxf(v, __shfl_xor(v, off, 64));
        mn[r] = fmaxf(m_r[r], v);
        corr[r] = __expf(m_r[r] - mn[r]);
        m_r[r] = mn[r];
      }
      float rs[4] = {0.f, 0.f, 0.f, 0.f};
#pragma unroll
      for (int n = 0; n < 4; ++n)
#pragma unroll
        for (int r = 0; r < 4; ++r) {
          float p = __expf(s[n][r] - mn[r]);
          rs[r] += p;
          Ps[w][(lhi * 4 + r) * PLDB + n * 16 + l15] = (bf16_t)p;
        }
#pragma unroll
      for (int r = 0; r < 4; ++r) {
        float v = rs[r];
#pragma unroll
        for (int off = 1; off < 16; off <<= 1) v += __shfl_xor(v, off, 64);
        l_r[r] = l_r[r] * corr[r] + v;
      }
#pragma unroll
      for (int n = 0; n < 8; ++n)
#pragma unroll
        for (int r = 0; r < 4; ++r) accO[n][r] *= corr[r];

      __builtin_amdgcn_s_setprio(1);
#pragma unroll
      for (int kc = 0; kc < 2; ++kc) {
        bf16x4 p0 = *(const bf16x4*)&Ps[w][l15 * PLDB + kc * 32 + lhi * 8];
        bf16x4 p1 = *(const bf16x4*)&Ps[w][l15 * PLDB + kc * 32 + lhi * 8 + 4];
        bf16x8 pf = __builtin_shufflevector(p0, p1, 0, 1, 2, 3, 4, 5, 6, 7);
#pragma unroll
        for (int n = 0; n < 8; ++n) {
          bf16x8 vf = *(const bf16x8*)&Vs[(n * 16 + l15) * VLDB + kc * 32 + lhi * 8];
          accO[n] = __builtin_amdgcn_mfma_f32_16x16x32_bf16(pf, vf, accO[n], 0, 0, 0);
        }
      }
      __builtin_amdgcn_s_setprio(0);

      __syncthreads();
      if (haveNext) WRITE_TILE();
      __syncthreads();
    }

    {
      float inv[4];
#pragma unroll
      for (int r = 0; r < 4; ++r) inv[r] = 1.0f / l_r[r];
#pragma unroll
      for (int n = 0; n < 8; ++n)
#pragma unroll
        for (int r = 0; r < 4; ++r) {
          size_t row = (size_t)(b * T_ + qt * 64 + w * 16 + lhi * 4 + r);
          Ob[row * (H_ * DH_) + h * DH_ + n * 16 + l15] = (bf16_t)(accO[n][r] * inv[r]);
        }
    }
  }
#undef LOAD_TILE
#undef WRITE_TILE
}

// ---------------- host ----------------
extern "C" void kernel_launch(void* const* d_in, const int* in_sizes, int n_in,
                              void* d_out, int out_size, void* d_ws, size_t ws_size,
                              hipStream_t stream) {
  (void)in_sizes; (void)n_in; (void)out_size; (void)ws_size;
  const float* x    = (const float*)d_in[0];
  const float* fr   = (const float*)d_in[1];
  // d_in[2] = mask (unused; causal handled analytically)
  const float* Wdq  = (const float*)d_in[3];
  const float* Wuq  = (const float*)d_in[4];
  const float* Wdkv = (const float*)d_in[5];
  const float* Wuk  = (const float*)d_in[6];
  const float* Wuv  = (const float*)d_in[7];
  const float* Wqr  = (const float*)d_in[8];
  const float* Wkr  = (const float*)d_in[9];
  const float* Wo   = (const float*)d_in[10];
  float* out = (float*)d_out;

  char* ws = (char*)d_ws;
  size_t off = 0;
  auto alloc = [&](size_t bytes) -> void* {
    void* p = ws + off;
    off += (bytes + 255) & ~(size_t)255;
    return p;
  };
  bf16_t* x_bf   = (bf16_t*)alloc((size_t)BT_ * DIM_ * 2);
  // concatenated Bt buffers (transposed weights)
  bf16_t* Bt1    = (bf16_t*)alloc((size_t)1152 * 2048 * 2);  // [Wdq(512) | Wdkv(512) | Wkr(128, zero-padded)]
  bf16_t* Bt2    = (bf16_t*)alloc((size_t)3072 * 512 * 2);   // [Wuq(2048) | Wqr(1024)]
  bf16_t* Bt3    = (bf16_t*)alloc((size_t)4096 * 512 * 2);   // [Wuk(2048) | Wuv(2048)]
  bf16_t* Wo_t   = (bf16_t*)alloc((size_t)2048 * 2048 * 2);
  bf16_t* q_c    = (bf16_t*)alloc((size_t)BT_ * 512 * 2);
  bf16_t* kv_c   = (bf16_t*)alloc((size_t)BT_ * 512 * 2);
  bf16_t* q_rb   = (bf16_t*)alloc((size_t)BT_ * 1024 * 2);
  bf16_t* k_rb   = (bf16_t*)alloc((size_t)BT_ * 64 * 2);
  bf16_t* Qbuf   = (bf16_t*)alloc((size_t)BT_ * QSTRIDE_ * 2);
  bf16_t* Kbuf   = (bf16_t*)alloc((size_t)BT_ * QSTRIDE_ * 2);
  bf16_t* Vbuf   = (bf16_t*)alloc((size_t)BT_ * 2048 * 2);
  bf16_t* Vt_g   = (bf16_t*)alloc((size_t)BT_ * 2048 * 2);
  bf16_t* AObuf  = (bf16_t*)alloc((size_t)BT_ * 2048 * 2);

  dim3 tb(32, 8);
  cast_f32_bf16<<<(BT_ * DIM_ / 4 + 255) / 256, 256, 0, stream>>>(x, x_bf, BT_ * DIM_ / 4);
  // Bt1: rows 0-511 Wdq^T, 512-1023 Wdkv^T, 1024-1151 Wkr^T (64 real + 64 zero)
  transpose_cast<<<dim3(64, 16), tb, 0, stream>>>(Wdq,  Bt1,                        2048, 512, 512);
  transpose_cast<<<dim3(64, 16), tb, 0, stream>>>(Wdkv, Bt1 + (size_t)512 * 2048,   2048, 512, 512);
  transpose_cast<<<dim3(64, 4),  tb, 0, stream>>>(Wkr,  Bt1 + (size_t)1024 * 2048,  2048, 64, 128);
  // Bt2: rows 0-2047 Wuq^T, 2048-3071 Wqr^T
  transpose_cast<<<dim3(16, 64), tb, 0, stream>>>(Wuq,  Bt2,                        512, 2048, 2048);
  transpose_cast<<<dim3(16, 32), tb, 0, stream>>>(Wqr,  Bt2 + (size_t)2048 * 512,   512, 1024, 1024);
  // Bt3: rows 0-2047 Wuk^T, 2048-4095 Wuv^T
  transpose_cast<<<dim3(16, 64), tb, 0, stream>>>(Wuk,  Bt3,                        512, 2048, 2048);
  transpose_cast<<<dim3(16, 64), tb, 0, stream>>>(Wuv,  Bt3 + (size_t)2048 * 512,   512, 2048, 2048);
  transpose_cast<<<dim3(64, 64), tb, 0, stream>>>(Wo,   Wo_t,                       2048, 2048, 2048);

  // fused projections
  gemm_bt<3><<<dim3(9, 32),  256, 0, stream>>>(x_bf, Bt1, q_c, kv_c, k_rb, BT_, 1088, 2048, 0);
  gemm_bt<4><<<dim3(24, 32), 256, 0, stream>>>(q_c,  Bt2, Qbuf, q_rb, nullptr, BT_, 3072, 512, 0);
  gemm_bt<5><<<dim3(32, 32), 256, 0, stream>>>(kv_c, Bt3, Kbuf, Vbuf, nullptr, BT_, 4096, 512, 0);

  transpose_v<<<2048, 256, 0, stream>>>(Vbuf, Vt_g);

  rope_q<<<(BT_ * H_ * 32) / 256, 256, 0, stream>>>(q_rb, fr, Qbuf);
  rope_k<<<(BT_ * 32) / 256, 256, 0, stream>>>(k_rb, fr, Kbuf);

  flash_attn3<<<512, 256, 0, stream>>>(Qbuf, Kbuf, Vt_g, AObuf);

  // output projection -> fp32
  gemm_bt<1><<<dim3(16, 32), 256, 0, stream>>>(AObuf, Wo_t, out, nullptr, nullptr, BT_, 2048, 2048, 2048);
}